// Round 9
// baseline (449.745 us; speedup 1.0000x reference)
//
#include <hip/hip_runtime.h>
#include <hip/hip_bf16.h>

#define S 2048
#define D 1024
#define NE 8
#define HF 4096
#define HH 8192
#define BK 32
#define ACT_ROWS 4224  // 4096 + 128 pad
#define MAXRB 40       // max 128-row blocks: 4096/128 + 8 - 1 = 39
#define NSPLIT 4

typedef __attribute__((ext_vector_type(8))) __bf16 bf16x8;
typedef __attribute__((ext_vector_type(4))) float f32x4;

__device__ __forceinline__ unsigned cvtpk(float lo, float hi) {
  unsigned r;
  asm("v_cvt_pk_bf16_f32 %0, %1, %2" : "=v"(r) : "v"(lo), "v"(hi));
  return r;  // RNE, lo in low 16
}
__device__ __forceinline__ unsigned bf16b(float f) {
  unsigned b = __float_as_uint(f);
  return (b + 0x7fffu + ((b >> 16) & 1u)) >> 16;  // RNE fp32->bf16 (finite)
}
__device__ __forceinline__ void gll16(const ushort* g, ushort* l) {
  __builtin_amdgcn_global_load_lds(
      (const __attribute__((address_space(1))) void*)g,
      (__attribute__((address_space(3))) void*)l, 16, 0, 0);
}

// ---- shared transpose tile body: [R][C] fp32 -> [C][R] bf16, one 64x64 tile ----
__device__ __forceinline__ void transpose_body(const float* __restrict__ Sp,
                                               ushort* __restrict__ Dp, int R, int C,
                                               int n0, int k0, unsigned (*T)[33]) {
  const int t = threadIdx.x;
  const int kp = t >> 4;         // 0..15
  const int nn = (t & 15) * 4;   // 0..60
#pragma unroll
  for (int j = 0; j < 2; ++j) {
    const int ka = k0 + 2 * kp + 32 * j;
    float4 a = *(const float4*)(Sp + (size_t)ka * C + n0 + nn);
    float4 b = *(const float4*)(Sp + (size_t)(ka + 1) * C + n0 + nn);
    T[nn + 0][kp + 16 * j] = cvtpk(a.x, b.x);
    T[nn + 1][kp + 16 * j] = cvtpk(a.y, b.y);
    T[nn + 2][kp + 16 * j] = cvtpk(a.z, b.z);
    T[nn + 3][kp + 16 * j] = cvtpk(a.w, b.w);
  }
  __syncthreads();
  const int n = t >> 2;
  const int kq = (t & 3) * 8;
  uint4 v0 = *(const uint4*)&T[n][kq];
  uint4 v1 = *(const uint4*)&T[n][kq + 4];
  uint4* o = (uint4*)(Dp + (size_t)(n0 + n) * R + k0 + kq * 2);
  o[0] = v0;
  o[1] = v1;
}

// ------- prep: transpose w1 (16384 blocks) + gate/x->bf16 (2048 blocks) -------
union PrepSmem {
  unsigned tr[64][33];
  float sm[4][NE];
};

__global__ __launch_bounds__(256) void prep_kernel(
    const float* __restrict__ w1, ushort* __restrict__ w1t,
    const float* __restrict__ x, const float* __restrict__ gw,
    const float* __restrict__ gb, ushort* __restrict__ xb,
    int* __restrict__ mi0, int* __restrict__ mi1,
    float* __restrict__ mw0, float* __restrict__ mw1) {
  __shared__ PrepSmem u;
  const int id = blockIdx.x;
  if (id < 16384) {  // w1 transpose: R=D, C=HH; 128 n-tiles x 16 k-tiles per expert
    const int e = id >> 11;
    const int rem = id & 2047;
    transpose_body(w1 + (size_t)e * D * HH, w1t + (size_t)e * D * HH, D, HH,
                   (rem & 127) * 64, (rem >> 7) * 64, u.tr);
    return;
  }
  // ---- gate for token t ----
  const int t = id - 16384;
  const int l = threadIdx.x;  // handles d = 4l..4l+3
  const float4 xv = ((const float4*)(x + (size_t)t * D))[l];
  uint2 wv = {cvtpk(xv.x, xv.y), cvtpk(xv.z, xv.w)};
  ((uint2*)(xb + (size_t)t * D))[l] = wv;

  float xa[4] = {xv.x, xv.y, xv.z, xv.w};
  float acc[NE];
#pragma unroll
  for (int e = 0; e < NE; ++e) acc[e] = 0.f;
  const float* g0 = gw + (size_t)(4 * l) * NE;
#pragma unroll
  for (int j = 0; j < 4; ++j)
#pragma unroll
    for (int e = 0; e < NE; ++e) acc[e] += xa[j] * g0[j * NE + e];
#pragma unroll
  for (int e = 0; e < NE; ++e) {
    float v = acc[e];
#pragma unroll
    for (int off = 32; off > 0; off >>= 1) v += __shfl_xor(v, off);
    acc[e] = v;
  }
  const int wid = l >> 6;
  if ((l & 63) == 0) {
#pragma unroll
    for (int e = 0; e < NE; ++e) u.sm[wid][e] = acc[e];
  }
  __syncthreads();
  if (l == 0) {
    float lg[NE];
#pragma unroll
    for (int e = 0; e < NE; ++e)
      lg[e] = u.sm[0][e] + u.sm[1][e] + u.sm[2][e] + u.sm[3][e] + gb[e];
    int i0 = 0; float m0 = lg[0];
#pragma unroll
    for (int e = 1; e < NE; ++e) if (lg[e] > m0) { m0 = lg[e]; i0 = e; }  // strict >: jax tie-break
    int i1 = -1; float m1 = -3.4e38f;
#pragma unroll
    for (int e = 0; e < NE; ++e) if (e != i0 && lg[e] > m1) { m1 = lg[e]; i1 = e; }
    float p = __expf(m1 - m0);
    float inv = 1.f / (1.f + p);
    mi0[t] = i0; mi1[t] = i1;
    mw0[t] = inv; mw1[t] = p * inv;
  }
}

// --- routing: counts + prefix + slots + compact rowblock table (one block) ---
__global__ __launch_bounds__(1024) void route_kernel(
    const int* __restrict__ mi0, const int* __restrict__ mi1,
    int* __restrict__ counts, int* __restrict__ basep, int* __restrict__ list_tok,
    int* __restrict__ mr0, int* __restrict__ mr1,
    int* __restrict__ rb_e, int* __restrict__ rb_row0, int* __restrict__ rb_n) {
  __shared__ int cnt[NE];
  __shared__ int cur[NE];
  const int t = threadIdx.x;
  if (t < NE) cnt[t] = 0;
  __syncthreads();
  const int e0a = mi0[t], e1a = mi1[t];
  const int e0b = mi0[t + 1024], e1b = mi1[t + 1024];
  atomicAdd(&cnt[e0a], 1); atomicAdd(&cnt[e1a], 1);
  atomicAdd(&cnt[e0b], 1); atomicAdd(&cnt[e1b], 1);
  __syncthreads();
  if (t == 0) {
    int s = 0;
#pragma unroll
    for (int e = 0; e < NE; ++e) { basep[e] = s; cur[e] = s; s += cnt[e]; }
    basep[NE] = s;
    int nrb = 0;
    for (int e = 0; e < NE; ++e)
      for (int r0 = 0; r0 < cnt[e]; r0 += 128) {
        rb_e[nrb] = e; rb_row0[nrb] = r0; ++nrb;
      }
    *rb_n = nrb;  // <= 39
  }
  if (t < NE) counts[t] = cnt[t];
  __syncthreads();
  int r;
  r = atomicAdd(&cur[e0a], 1); list_tok[r] = t; mr0[t] = r;
  r = atomicAdd(&cur[e1a], 1); list_tok[r] = t; mr1[t] = r;
  r = atomicAdd(&cur[e0b], 1); list_tok[r] = t + 1024; mr0[t + 1024] = r;
  r = atomicAdd(&cur[e1b], 1); list_tok[r] = t + 1024; mr1[t + 1024] = r;
}

// -------- GEMM1 + SwiGLU (blocks 0..64*MAXRB) fused with w2 transpose (rest) --------
union G1Smem {
  struct { ushort As[2][128][BK]; ushort Bs[2][128][BK]; } g;
  unsigned tr[64][33];
};

__global__ __launch_bounds__(256) void gemm1_tw2_kernel(
    const ushort* __restrict__ xb, const ushort* __restrict__ w1t,
    const float* __restrict__ b1, const int* __restrict__ counts,
    const int* __restrict__ basep, const int* __restrict__ list_tok,
    const int* __restrict__ rb_e, const int* __restrict__ rb_row0,
    const int* __restrict__ rb_n, ushort* __restrict__ act_buf,
    const float* __restrict__ w2, ushort* __restrict__ w2t) {
  __shared__ G1Smem u;
  const int id = blockIdx.x;
  if (id >= 64 * MAXRB) {  // w2 transpose: R=HF, C=D; 16 n-tiles x 64 k-tiles per expert
    const int id2 = id - 64 * MAXRB;
    const int e = id2 >> 10;
    const int rem = id2 & 1023;
    transpose_body(w2 + (size_t)e * HF * D, w2t + (size_t)e * HF * D, HF, D,
                   (rem & 15) * 64, (rem >> 4) * 64, u.tr);
    return;
  }
  const int rb = id >> 6;
  if (rb >= *rb_n) return;
  const int jt = (id & 63) * 64;
  const int e = rb_e[rb];
  const int row0 = rb_row0[rb];
  const int cnt = counts[e];
  const ushort* __restrict__ W = w1t + (size_t)e * D * HH;  // [n=8192][k=1024] bf16
  const int gbase = basep[e];

  const int tid = threadIdx.x;
  const int w = tid >> 6;
  const int i = tid & 63;

  const int rA0 = w * 32 + (i >> 2);
  const int rA1 = rA0 + 16;
  int s0 = row0 + rA0; if (s0 >= cnt) s0 = cnt - 1;
  int s1 = row0 + rA1; if (s1 >= cnt) s1 = cnt - 1;
  const ushort* pa0 = xb + (size_t)list_tok[gbase + s0] * D + (i & 3) * 8;
  const ushort* pa1 = xb + (size_t)list_tok[gbase + s1] * D + (i & 3) * 8;
  const ushort* pb0 = W + ((size_t)(rA0 >> 6) * HF + jt + (rA0 & 63)) * D + (i & 3) * 8;
  const ushort* pb1 = W + ((size_t)(rA1 >> 6) * HF + jt + (rA1 & 63)) * D + (i & 3) * 8;

  const int wm = (w >> 1) * 64;
  const int wn = (w & 1) * 32;
  const int lr = i & 15;
  const int kg = i >> 4;

  f32x4 acc[2][4][2] = {};  // [half][mi][ni]

  gll16(pa0, &u.g.As[0][w * 32][0]);
  gll16(pa1, &u.g.As[0][w * 32 + 16][0]);
  gll16(pb0, &u.g.Bs[0][w * 32][0]);
  gll16(pb1, &u.g.Bs[0][w * 32 + 16][0]);
  __syncthreads();

  int cur = 0;
#pragma unroll 1
  for (int it = 0; it < D / BK; ++it) {
    if (it + 1 < D / BK) {
      const int ko = (it + 1) * BK;
      gll16(pa0 + ko, &u.g.As[cur ^ 1][w * 32][0]);
      gll16(pa1 + ko, &u.g.As[cur ^ 1][w * 32 + 16][0]);
      gll16(pb0 + ko, &u.g.Bs[cur ^ 1][w * 32][0]);
      gll16(pb1 + ko, &u.g.Bs[cur ^ 1][w * 32 + 16][0]);
    }
    bf16x8 af[4], bfr[2][2];
#pragma unroll
    for (int mi = 0; mi < 4; ++mi)
      af[mi] = *(const bf16x8*)&u.g.As[cur][wm + mi * 16 + lr][kg * 8];
#pragma unroll
    for (int h = 0; h < 2; ++h)
#pragma unroll
      for (int ni = 0; ni < 2; ++ni)
        bfr[h][ni] = *(const bf16x8*)&u.g.Bs[cur][h * 64 + wn + ni * 16 + lr][kg * 8];
#pragma unroll
    for (int h = 0; h < 2; ++h)
#pragma unroll
      for (int mi = 0; mi < 4; ++mi)
#pragma unroll
        for (int ni = 0; ni < 2; ++ni)
          acc[h][mi][ni] = __builtin_amdgcn_mfma_f32_16x16x32_bf16(af[mi], bfr[h][ni],
                                                                   acc[h][mi][ni], 0, 0, 0);
    __syncthreads();
    cur ^= 1;
  }

#pragma unroll
  for (int mi = 0; mi < 4; ++mi)
#pragma unroll
    for (int ni = 0; ni < 2; ++ni) {
      const int c = jt + wn + ni * 16 + lr;
      const float bx = b1[(size_t)e * HH + c];
      const float bg = b1[(size_t)e * HH + HF + c];
      f32x4 vx = acc[0][mi][ni];
      f32x4 vg = acc[1][mi][ni];
#pragma unroll
      for (int q = 0; q < 4; ++q) {
        const int slot = row0 + wm + mi * 16 + kg * 4 + q;
        if (slot < cnt) {
          float xv = vx[q] + bx;
          float g = vg[q] + bg;
          float a = g / (1.f + __expf(-g)) * xv;
          act_buf[(size_t)(gbase + slot) * HF + c] = (ushort)bf16b(a);
        }
      }
    }
}

// -------- GEMM2 (K-split 4): oe[split] = act @ W2[e], bf16 stores --------
// grid: x = jt (fastest, 8), y = compact rowblock id, z = split
__global__ __launch_bounds__(256) void gemm2_kernel(
    const ushort* __restrict__ act_buf, const ushort* __restrict__ w2t,
    const int* __restrict__ counts, const int* __restrict__ basep,
    const int* __restrict__ rb_e, const int* __restrict__ rb_row0,
    const int* __restrict__ rb_n, ushort* __restrict__ oe) {
  const int rb = blockIdx.y;
  if (rb >= *rb_n) return;
  const int e = rb_e[rb];
  const int row0 = rb_row0[rb];
  const int cnt = counts[e];
  const int split = blockIdx.z;
  const int jt = blockIdx.x * 128;
  const ushort* __restrict__ W = w2t + (size_t)e * HF * D;  // [n=1024][kf=4096] bf16
  const int gbase = basep[e];

  __shared__ ushort As[2][128][BK];
  __shared__ ushort Bs[2][128][BK];

  const int tid = threadIdx.x;
  const int w = tid >> 6;
  const int i = tid & 63;

  const int r0 = w * 32 + (i >> 2);
  const size_t kbase = (size_t)split * (HF / NSPLIT);
  const ushort* pa0 = act_buf + (size_t)(gbase + row0 + r0) * HF + kbase + (i & 3) * 8;
  const ushort* pa1 = pa0 + (size_t)16 * HF;
  const ushort* pb0 = W + (size_t)(jt + r0) * HF + kbase + (i & 3) * 8;
  const ushort* pb1 = pb0 + (size_t)16 * HF;

  const int wm = (w >> 1) * 64;
  const int wn = (w & 1) * 64;
  const int lr = i & 15;
  const int kg = i >> 4;

  f32x4 acc[4][4] = {};

  gll16(pa0, &As[0][w * 32][0]);
  gll16(pa1, &As[0][w * 32 + 16][0]);
  gll16(pb0, &Bs[0][w * 32][0]);
  gll16(pb1, &Bs[0][w * 32 + 16][0]);
  __syncthreads();

  int cur = 0;
#pragma unroll 1
  for (int it = 0; it < (HF / NSPLIT) / BK; ++it) {
    if (it + 1 < (HF / NSPLIT) / BK) {
      const int ko = (it + 1) * BK;
      gll16(pa0 + ko, &As[cur ^ 1][w * 32][0]);
      gll16(pa1 + ko, &As[cur ^ 1][w * 32 + 16][0]);
      gll16(pb0 + ko, &Bs[cur ^ 1][w * 32][0]);
      gll16(pb1 + ko, &Bs[cur ^ 1][w * 32 + 16][0]);
    }
    bf16x8 af[4], bfr[4];
#pragma unroll
    for (int mi = 0; mi < 4; ++mi)
      af[mi] = *(const bf16x8*)&As[cur][wm + mi * 16 + lr][kg * 8];
#pragma unroll
    for (int ni = 0; ni < 4; ++ni)
      bfr[ni] = *(const bf16x8*)&Bs[cur][wn + ni * 16 + lr][kg * 8];
#pragma unroll
    for (int mi = 0; mi < 4; ++mi)
#pragma unroll
      for (int ni = 0; ni < 4; ++ni)
        acc[mi][ni] = __builtin_amdgcn_mfma_f32_16x16x32_bf16(af[mi], bfr[ni],
                                                              acc[mi][ni], 0, 0, 0);
    __syncthreads();
    cur ^= 1;
  }

#pragma unroll
  for (int mi = 0; mi < 4; ++mi)
#pragma unroll
    for (int ni = 0; ni < 4; ++ni) {
      f32x4 v = acc[mi][ni];
#pragma unroll
      for (int q = 0; q < 4; ++q) {
        const int slot = row0 + wm + mi * 16 + kg * 4 + q;
        if (slot < cnt)
          oe[((size_t)split * ACT_ROWS + gbase + slot) * D + jt + wn + ni * 16 + lr] =
              (ushort)bf16b(v[q]);
      }
    }
}

// ---- combine: out[t] = w0*(sum_s oe[s][r0] + b2[e0]) + w1*(sum_s oe[s][r1] + b2[e1]) ----
__global__ void combine_kernel(const ushort* __restrict__ oe,
                               const int* __restrict__ mr0, const int* __restrict__ mr1,
                               const float* __restrict__ mw0, const float* __restrict__ mw1,
                               const int* __restrict__ mi0, const int* __restrict__ mi1,
                               const float* __restrict__ b2, float* __restrict__ out) {
  const int t = blockIdx.x;
  const int l = threadIdx.x;  // 4 elems per thread
  const float w0 = mw0[t], w1 = mw1[t];
  const int r0 = mr0[t], r1 = mr1[t];
  float a0[4] = {0.f, 0.f, 0.f, 0.f}, a1[4] = {0.f, 0.f, 0.f, 0.f};
#pragma unroll
  for (int s = 0; s < NSPLIT; ++s) {
    uint2 u0 = *(const uint2*)(oe + ((size_t)s * ACT_ROWS + r0) * D + l * 4);
    uint2 u1 = *(const uint2*)(oe + ((size_t)s * ACT_ROWS + r1) * D + l * 4);
    a0[0] += __uint_as_float(u0.x << 16);
    a0[1] += __uint_as_float(u0.x & 0xffff0000u);
    a0[2] += __uint_as_float(u0.y << 16);
    a0[3] += __uint_as_float(u0.y & 0xffff0000u);
    a1[0] += __uint_as_float(u1.x << 16);
    a1[1] += __uint_as_float(u1.x & 0xffff0000u);
    a1[2] += __uint_as_float(u1.y << 16);
    a1[3] += __uint_as_float(u1.y & 0xffff0000u);
  }
  float4 c0 = ((const float4*)(b2 + (size_t)mi0[t] * D))[l];
  float4 c1 = ((const float4*)(b2 + (size_t)mi1[t] * D))[l];
  float4 r;
  r.x = w0 * (a0[0] + c0.x) + w1 * (a1[0] + c1.x);
  r.y = w0 * (a0[1] + c0.y) + w1 * (a1[1] + c1.y);
  r.z = w0 * (a0[2] + c0.z) + w1 * (a1[2] + c1.z);
  r.w = w0 * (a0[3] + c0.w) + w1 * (a1[3] + c1.w);
  ((float4*)(out + (size_t)t * D))[l] = r;
}

extern "C" void kernel_launch(void* const* d_in, const int* in_sizes, int n_in,
                              void* d_out, int out_size, void* d_ws, size_t ws_size,
                              hipStream_t stream) {
  const float* x  = (const float*)d_in[0];
  const float* gw = (const float*)d_in[1];
  const float* gb = (const float*)d_in[2];
  const float* w1 = (const float*)d_in[3];
  const float* b1 = (const float*)d_in[4];
  const float* w2 = (const float*)d_in[5];
  const float* b2 = (const float*)d_in[6];
  float* out = (float*)d_out;

  char* ws = (char*)d_ws;
  int*   counts   = (int*)(ws + 0);
  int*   basep    = (int*)(ws + 64);
  int*   rb_n     = (int*)(ws + 128);
  int*   rb_e     = (int*)(ws + 192);                       // 40 ints
  int*   rb_row0  = (int*)(ws + 384);                       // 40 ints
  int*   mi0      = (int*)(ws + 1024);
  int*   mi1      = (int*)(ws + 1024 + 1 * 8192);
  int*   mr0      = (int*)(ws + 1024 + 2 * 8192);
  int*   mr1      = (int*)(ws + 1024 + 3 * 8192);
  float* mw0      = (float*)(ws + 1024 + 4 * 8192);
  float* mw1      = (float*)(ws + 1024 + 5 * 8192);
  int*   list_tok = (int*)(ws + 1024 + 6 * 8192);           // 16384 B -> ends 66560
  ushort* xb      = (ushort*)(ws + 66560);                  // 4 MB
  ushort* act_buf = (ushort*)(ws + 4260864);                // 34.6 MB (4224 x 4096 bf16)
  ushort* oe      = (ushort*)(ws + 38863872);               // 34.6 MB (4 x 4224 x 1024 bf16)
  ushort* w1t     = (ushort*)(ws + 73466880);               // 134 MB
  ushort* w2t     = (ushort*)(ws + 207684608);              // 67 MB (end: 274.8 MB)

  prep_kernel<<<16384 + S, 256, 0, stream>>>(w1, w1t, x, gw, gb, xb, mi0, mi1, mw0, mw1);
  route_kernel<<<1, 1024, 0, stream>>>(mi0, mi1, counts, basep, list_tok, mr0, mr1,
                                       rb_e, rb_row0, rb_n);
  gemm1_tw2_kernel<<<64 * MAXRB + NE * 1024, 256, 0, stream>>>(
      xb, w1t, b1, counts, basep, list_tok, rb_e, rb_row0, rb_n, act_buf, w2, w2t);
  gemm2_kernel<<<dim3(8, MAXRB, NSPLIT), 256, 0, stream>>>(act_buf, w2t, counts, basep,
                                                           rb_e, rb_row0, rb_n, oe);
  combine_kernel<<<S, 256, 0, stream>>>(oe, mr0, mr1, mw0, mw1, mi0, mi1, b2, out);
}

// Round 10
// 347.379 us; speedup vs baseline: 1.2947x; 1.2947x over previous
//
#include <hip/hip_runtime.h>
#include <hip/hip_bf16.h>

#define S 2048
#define D 1024
#define NE 8
#define HF 4096
#define HH 8192
#define BK 32
#define ACT_ROWS 4224  // 4096 + 128 pad
#define MAXRB 40       // max 128-row blocks: 4096/128 + 8 - 1 = 39

typedef __attribute__((ext_vector_type(8))) __bf16 bf16x8;
typedef __attribute__((ext_vector_type(16))) float f32x16;

__device__ __forceinline__ unsigned cvtpk(float lo, float hi) {
  unsigned r;
  asm("v_cvt_pk_bf16_f32 %0, %1, %2" : "=v"(r) : "v"(lo), "v"(hi));
  return r;  // RNE, lo in low 16
}
__device__ __forceinline__ unsigned bf16b(float f) {
  unsigned b = __float_as_uint(f);
  return (b + 0x7fffu + ((b >> 16) & 1u)) >> 16;  // RNE fp32->bf16 (finite)
}
__device__ __forceinline__ void gll16(const ushort* g, ushort* l) {
  __builtin_amdgcn_global_load_lds(
      (const __attribute__((address_space(1))) void*)g,
      (__attribute__((address_space(3))) void*)l, 16, 0, 0);
}

// ------------- W: [E][R][C] fp32 -> [E][C][R] bf16 (transpose + convert) -------------
__global__ __launch_bounds__(256) void transpose_convert(const float* __restrict__ src,
                                                         ushort* __restrict__ dst,
                                                         int R, int C) {
  const int e = blockIdx.z;
  const int n0 = blockIdx.x * 64;
  const int k0 = blockIdx.y * 64;
  const float* Sp = src + (size_t)e * R * C;
  ushort* Dp = dst + (size_t)e * R * C;
  __shared__ unsigned T[64][33];
  const int t = threadIdx.x;
  const int kp = t >> 4;         // 0..15
  const int nn = (t & 15) * 4;   // 0..60
#pragma unroll
  for (int j = 0; j < 2; ++j) {
    const int ka = k0 + 2 * kp + 32 * j;
    float4 a = *(const float4*)(Sp + (size_t)ka * C + n0 + nn);
    float4 b = *(const float4*)(Sp + (size_t)(ka + 1) * C + n0 + nn);
    T[nn + 0][kp + 16 * j] = cvtpk(a.x, b.x);
    T[nn + 1][kp + 16 * j] = cvtpk(a.y, b.y);
    T[nn + 2][kp + 16 * j] = cvtpk(a.z, b.z);
    T[nn + 3][kp + 16 * j] = cvtpk(a.w, b.w);
  }
  __syncthreads();
  const int n = t >> 2;
  const int kq = (t & 3) * 8;
  uint4 v0 = *(const uint4*)&T[n][kq];
  uint4 v1 = *(const uint4*)&T[n][kq + 4];
  uint4* out = (uint4*)(Dp + (size_t)(n0 + n) * R + k0 + kq * 2);
  out[0] = v0;
  out[1] = v1;
}

// ------- gating + x->bf16 fused: one block (256 thr) per token -------
__global__ __launch_bounds__(256) void gate_kernel(
    const float* __restrict__ x, const float* __restrict__ gw,
    const float* __restrict__ gb, ushort* __restrict__ xb,
    int* __restrict__ mi0, int* __restrict__ mi1,
    float* __restrict__ mw0, float* __restrict__ mw1) {
  const int t = blockIdx.x;
  const int l = threadIdx.x;  // 0..255, handles d = 4l..4l+3
  const float4 xv = ((const float4*)(x + (size_t)t * D))[l];
  uint2 wv = {cvtpk(xv.x, xv.y), cvtpk(xv.z, xv.w)};
  ((uint2*)(xb + (size_t)t * D))[l] = wv;

  float xa[4] = {xv.x, xv.y, xv.z, xv.w};
  float acc[NE];
#pragma unroll
  for (int e = 0; e < NE; ++e) acc[e] = 0.f;
  const float* g0 = gw + (size_t)(4 * l) * NE;
#pragma unroll
  for (int j = 0; j < 4; ++j)
#pragma unroll
    for (int e = 0; e < NE; ++e) acc[e] += xa[j] * g0[j * NE + e];
#pragma unroll
  for (int e = 0; e < NE; ++e) {
    float v = acc[e];
#pragma unroll
    for (int off = 32; off > 0; off >>= 1) v += __shfl_xor(v, off);
    acc[e] = v;
  }
  __shared__ float sm[4][NE];
  const int wid = l >> 6;
  if ((l & 63) == 0) {
#pragma unroll
    for (int e = 0; e < NE; ++e) sm[wid][e] = acc[e];
  }
  __syncthreads();
  if (l == 0) {
    float lg[NE];
#pragma unroll
    for (int e = 0; e < NE; ++e)
      lg[e] = sm[0][e] + sm[1][e] + sm[2][e] + sm[3][e] + gb[e];
    int i0 = 0; float m0 = lg[0];
#pragma unroll
    for (int e = 1; e < NE; ++e) if (lg[e] > m0) { m0 = lg[e]; i0 = e; }  // strict >: jax tie-break
    int i1 = -1; float m1 = -3.4e38f;
#pragma unroll
    for (int e = 0; e < NE; ++e) if (e != i0 && lg[e] > m1) { m1 = lg[e]; i1 = e; }
    float p = __expf(m1 - m0);
    float inv = 1.f / (1.f + p);
    mi0[t] = i0; mi1[t] = i1;
    mw0[t] = inv; mw1[t] = p * inv;
  }
}

// --- routing: counts + prefix + slots + compact rowblock table (one block) ---
__global__ __launch_bounds__(1024) void route_kernel(
    const int* __restrict__ mi0, const int* __restrict__ mi1,
    int* __restrict__ counts, int* __restrict__ basep, int* __restrict__ list_tok,
    int* __restrict__ mr0, int* __restrict__ mr1,
    int* __restrict__ rb_e, int* __restrict__ rb_row0, int* __restrict__ rb_n) {
  __shared__ int cnt[NE];
  __shared__ int cur[NE];
  const int t = threadIdx.x;
  if (t < NE) cnt[t] = 0;
  __syncthreads();
  const int e0a = mi0[t], e1a = mi1[t];
  const int e0b = mi0[t + 1024], e1b = mi1[t + 1024];
  atomicAdd(&cnt[e0a], 1); atomicAdd(&cnt[e1a], 1);
  atomicAdd(&cnt[e0b], 1); atomicAdd(&cnt[e1b], 1);
  __syncthreads();
  if (t == 0) {
    int s = 0;
#pragma unroll
    for (int e = 0; e < NE; ++e) { basep[e] = s; cur[e] = s; s += cnt[e]; }
    basep[NE] = s;
    int nrb = 0;
    for (int e = 0; e < NE; ++e)
      for (int r0 = 0; r0 < cnt[e]; r0 += 128) {
        rb_e[nrb] = e; rb_row0[nrb] = r0; ++nrb;
      }
    *rb_n = nrb;  // <= 39
  }
  if (t < NE) counts[t] = cnt[t];
  __syncthreads();
  int r;
  r = atomicAdd(&cur[e0a], 1); list_tok[r] = t; mr0[t] = r;
  r = atomicAdd(&cur[e1a], 1); list_tok[r] = t; mr1[t] = r;
  r = atomicAdd(&cur[e0b], 1); list_tok[r] = t + 1024; mr0[t + 1024] = r;
  r = atomicAdd(&cur[e1b], 1); list_tok[r] = t + 1024; mr1[t + 1024] = r;
}

// -------- GEMM1 + SwiGLU: 128 rows x 64 act-cols, 32x32x16 MFMA --------
// LDS granule swizzle: row r, physical 16B-slot g holds logical granule g^(r&3)
// (pre-swizzled global source; gll16 dest linear; reads XOR the same way)
__global__ __launch_bounds__(256) void gemm1_kernel(
    const ushort* __restrict__ xb, const ushort* __restrict__ w1t,
    const float* __restrict__ b1, const int* __restrict__ counts,
    const int* __restrict__ basep, const int* __restrict__ list_tok,
    const int* __restrict__ rb_e, const int* __restrict__ rb_row0,
    const int* __restrict__ rb_n, ushort* __restrict__ act_buf) {
  const int rb = blockIdx.y;
  if (rb >= *rb_n) return;
  const int e = rb_e[rb];
  const int row0 = rb_row0[rb];
  const int cnt = counts[e];
  const int jt = blockIdx.x * 64;
  const ushort* __restrict__ W = w1t + (size_t)e * D * HH;  // [n=8192][k=1024] bf16
  const int gbase = basep[e];

  __shared__ ushort As[2][128][BK];
  __shared__ ushort Bs[2][128][BK];  // rows 0..63: x-half col jt+n ; 64..127: gate-half

  const int tid = threadIdx.x;
  const int w = tid >> 6;
  const int i = tid & 63;

  const int rA0 = w * 32 + (i >> 2);
  const int rA1 = rA0 + 16;              // (rA1 & 3) == (rA0 & 3)
  const int gsw = ((i & 3) ^ (rA0 & 3)) * 8;  // swizzled source granule offset (elems)
  int s0 = row0 + rA0; if (s0 >= cnt) s0 = cnt - 1;
  int s1 = row0 + rA1; if (s1 >= cnt) s1 = cnt - 1;
  const ushort* pa0 = xb + (size_t)list_tok[gbase + s0] * D + gsw;
  const ushort* pa1 = xb + (size_t)list_tok[gbase + s1] * D + gsw;
  const ushort* pb0 = W + ((size_t)(rA0 >> 6) * HF + jt + (rA0 & 63)) * D + gsw;
  const ushort* pb1 = W + ((size_t)(rA1 >> 6) * HF + jt + (rA1 & 63)) * D + gsw;

  const int wm = (w >> 1) * 64;
  const int wn = (w & 1) * 32;
  const int l31 = i & 31;
  const int khg = i >> 5;   // k sub-group of the 32x32x16 fragment

  f32x16 acc[2][2] = {};  // [half][mi]

  gll16(pa0, &As[0][w * 32][0]);
  gll16(pa1, &As[0][w * 32 + 16][0]);
  gll16(pb0, &Bs[0][w * 32][0]);
  gll16(pb1, &Bs[0][w * 32 + 16][0]);
  __syncthreads();

  int cur = 0;
#pragma unroll 1
  for (int it = 0; it < D / BK; ++it) {
    if (it + 1 < D / BK) {
      const int ko = (it + 1) * BK;
      gll16(pa0 + ko, &As[cur ^ 1][w * 32][0]);
      gll16(pa1 + ko, &As[cur ^ 1][w * 32 + 16][0]);
      gll16(pb0 + ko, &Bs[cur ^ 1][w * 32][0]);
      gll16(pb1 + ko, &Bs[cur ^ 1][w * 32 + 16][0]);
    }
    bf16x8 af[2][2], bfr[2][2];  // [mi][kh], [half][kh]
#pragma unroll
    for (int kh = 0; kh < 2; ++kh) {
      const int p8 = (((kh << 1) | khg) ^ (l31 & 3)) * 8;  // read-side XOR
#pragma unroll
      for (int mi = 0; mi < 2; ++mi)
        af[mi][kh] = *(const bf16x8*)&As[cur][wm + mi * 32 + l31][p8];
#pragma unroll
      for (int h = 0; h < 2; ++h)
        bfr[h][kh] = *(const bf16x8*)&Bs[cur][h * 64 + wn + l31][p8];
    }
#pragma unroll
    for (int h = 0; h < 2; ++h)
#pragma unroll
      for (int mi = 0; mi < 2; ++mi)
#pragma unroll
        for (int kh = 0; kh < 2; ++kh)
          acc[h][mi] = __builtin_amdgcn_mfma_f32_32x32x16_bf16(af[mi][kh], bfr[h][kh],
                                                               acc[h][mi], 0, 0, 0);
    __syncthreads();
    cur ^= 1;
  }

  // C/D (32x32): col = lane&31, row = (reg&3) + 8*(reg>>2) + 4*(lane>>5)
  const int c = jt + wn + l31;
  const float bx = b1[(size_t)e * HH + c];
  const float bg = b1[(size_t)e * HH + HF + c];
#pragma unroll
  for (int mi = 0; mi < 2; ++mi)
#pragma unroll
    for (int r = 0; r < 16; ++r) {
      const int slot = row0 + wm + mi * 32 + (r & 3) + 8 * (r >> 2) + 4 * khg;
      if (slot < cnt) {
        float xv = acc[0][mi][r] + bx;
        float g = acc[1][mi][r] + bg;
        float a = g / (1.f + __expf(-g)) * xv;
        act_buf[(size_t)(gbase + slot) * HF + c] = (ushort)bf16b(a);
      }
    }
}

// -------------------- GEMM2 (K-split 2): oe[split] = act @ W2[e], 32x32x16 --------------------
// grid: x = jt (fastest, 8), y = compact rowblock id, z = split
__global__ __launch_bounds__(256) void gemm2_kernel(
    const ushort* __restrict__ act_buf, const ushort* __restrict__ w2t,
    const int* __restrict__ counts, const int* __restrict__ basep,
    const int* __restrict__ rb_e, const int* __restrict__ rb_row0,
    const int* __restrict__ rb_n, float* __restrict__ oe) {
  const int rb = blockIdx.y;
  if (rb >= *rb_n) return;
  const int e = rb_e[rb];
  const int row0 = rb_row0[rb];
  const int cnt = counts[e];
  const int split = blockIdx.z;
  const int jt = blockIdx.x * 128;
  const ushort* __restrict__ W = w2t + (size_t)e * HF * D;  // [n=1024][kf=4096] bf16
  const int gbase = basep[e];

  __shared__ ushort As[2][128][BK];
  __shared__ ushort Bs[2][128][BK];

  const int tid = threadIdx.x;
  const int w = tid >> 6;
  const int i = tid & 63;

  const int r0 = w * 32 + (i >> 2);
  const int gsw = ((i & 3) ^ (r0 & 3)) * 8;
  const size_t kbase = (size_t)split * (HF / 2);
  const ushort* pa0 = act_buf + (size_t)(gbase + row0 + r0) * HF + kbase + gsw;
  const ushort* pa1 = pa0 + (size_t)16 * HF;
  const ushort* pb0 = W + (size_t)(jt + r0) * HF + kbase + gsw;
  const ushort* pb1 = pb0 + (size_t)16 * HF;

  const int wm = (w >> 1) * 64;
  const int wn = (w & 1) * 64;
  const int l31 = i & 31;
  const int khg = i >> 5;

  f32x16 acc[2][2] = {};  // [mi][ni]

  gll16(pa0, &As[0][w * 32][0]);
  gll16(pa1, &As[0][w * 32 + 16][0]);
  gll16(pb0, &Bs[0][w * 32][0]);
  gll16(pb1, &Bs[0][w * 32 + 16][0]);
  __syncthreads();

  int cur = 0;
#pragma unroll 1
  for (int it = 0; it < (HF / 2) / BK; ++it) {
    if (it + 1 < (HF / 2) / BK) {
      const int ko = (it + 1) * BK;
      gll16(pa0 + ko, &As[cur ^ 1][w * 32][0]);
      gll16(pa1 + ko, &As[cur ^ 1][w * 32 + 16][0]);
      gll16(pb0 + ko, &Bs[cur ^ 1][w * 32][0]);
      gll16(pb1 + ko, &Bs[cur ^ 1][w * 32 + 16][0]);
    }
    bf16x8 af[2][2], bfr[2][2];  // [mi][kh], [ni][kh]
#pragma unroll
    for (int kh = 0; kh < 2; ++kh) {
      const int p8 = (((kh << 1) | khg) ^ (l31 & 3)) * 8;
#pragma unroll
      for (int mi = 0; mi < 2; ++mi)
        af[mi][kh] = *(const bf16x8*)&As[cur][wm + mi * 32 + l31][p8];
#pragma unroll
      for (int ni = 0; ni < 2; ++ni)
        bfr[ni][kh] = *(const bf16x8*)&Bs[cur][wn + ni * 32 + l31][p8];
    }
#pragma unroll
    for (int mi = 0; mi < 2; ++mi)
#pragma unroll
      for (int ni = 0; ni < 2; ++ni)
#pragma unroll
        for (int kh = 0; kh < 2; ++kh)
          acc[mi][ni] = __builtin_amdgcn_mfma_f32_32x32x16_bf16(af[mi][kh], bfr[ni][kh],
                                                                acc[mi][ni], 0, 0, 0);
    __syncthreads();
    cur ^= 1;
  }

#pragma unroll
  for (int mi = 0; mi < 2; ++mi)
#pragma unroll
    for (int ni = 0; ni < 2; ++ni)
#pragma unroll
      for (int r = 0; r < 16; ++r) {
        const int slot = row0 + wm + mi * 32 + (r & 3) + 8 * (r >> 2) + 4 * khg;
        if (slot < cnt)
          oe[((size_t)split * ACT_ROWS + gbase + slot) * D + jt + wn + ni * 32 + l31] =
              acc[mi][ni][r];
      }
}

// ---------------- combine: out[t] = w0*(oe0[r0]+oe1[r0]+b2[e0]) + w1*(...) ----------------
__global__ void combine_kernel(const float* __restrict__ oe,
                               const int* __restrict__ mr0, const int* __restrict__ mr1,
                               const float* __restrict__ mw0, const float* __restrict__ mw1,
                               const int* __restrict__ mi0, const int* __restrict__ mi1,
                               const float* __restrict__ b2, float* __restrict__ out) {
  const int t = blockIdx.x;
  const int l = threadIdx.x;
  const float w0 = mw0[t], w1 = mw1[t];
  const float4* p00 = (const float4*)(oe + (size_t)mr0[t] * D);
  const float4* p01 = (const float4*)(oe + ((size_t)ACT_ROWS + mr0[t]) * D);
  const float4* p10 = (const float4*)(oe + (size_t)mr1[t] * D);
  const float4* p11 = (const float4*)(oe + ((size_t)ACT_ROWS + mr1[t]) * D);
  const float4* c0 = (const float4*)(b2 + (size_t)mi0[t] * D);
  const float4* c1 = (const float4*)(b2 + (size_t)mi1[t] * D);
  float4 A0 = p00[l], A1 = p01[l], B0 = p10[l], B1 = p11[l], C = c0[l], E2 = c1[l];
  float4 r;
  r.x = w0 * (A0.x + A1.x + C.x) + w1 * (B0.x + B1.x + E2.x);
  r.y = w0 * (A0.y + A1.y + C.y) + w1 * (B0.y + B1.y + E2.y);
  r.z = w0 * (A0.z + A1.z + C.z) + w1 * (B0.z + B1.z + E2.z);
  r.w = w0 * (A0.w + A1.w + C.w) + w1 * (B0.w + B1.w + E2.w);
  ((float4*)(out + (size_t)t * D))[l] = r;
}

extern "C" void kernel_launch(void* const* d_in, const int* in_sizes, int n_in,
                              void* d_out, int out_size, void* d_ws, size_t ws_size,
                              hipStream_t stream) {
  const float* x  = (const float*)d_in[0];
  const float* gw = (const float*)d_in[1];
  const float* gb = (const float*)d_in[2];
  const float* w1 = (const float*)d_in[3];
  const float* b1 = (const float*)d_in[4];
  const float* w2 = (const float*)d_in[5];
  const float* b2 = (const float*)d_in[6];
  float* out = (float*)d_out;

  char* ws = (char*)d_ws;
  int*   counts   = (int*)(ws + 0);
  int*   basep    = (int*)(ws + 64);
  int*   rb_n     = (int*)(ws + 128);
  int*   rb_e     = (int*)(ws + 192);                       // 40 ints
  int*   rb_row0  = (int*)(ws + 384);                       // 40 ints
  int*   mi0      = (int*)(ws + 1024);
  int*   mi1      = (int*)(ws + 1024 + 1 * 8192);
  int*   mr0      = (int*)(ws + 1024 + 2 * 8192);
  int*   mr1      = (int*)(ws + 1024 + 3 * 8192);
  float* mw0      = (float*)(ws + 1024 + 4 * 8192);
  float* mw1      = (float*)(ws + 1024 + 5 * 8192);
  int*   list_tok = (int*)(ws + 1024 + 6 * 8192);           // 16384 B -> ends 66560
  ushort* xb      = (ushort*)(ws + 66560);                  // 4 MB
  ushort* act_buf = (ushort*)(ws + 4260864);                // 34.6 MB (4224 x 4096 bf16)
  float*  oe      = (float*)(ws + 38863872);                // 34.6 MB (2 x 4224 x 1024 f32)
  ushort* w1t     = (ushort*)(ws + 73466880);               // 134 MB
  ushort* w2t     = (ushort*)(ws + 207684608);              // 67 MB (end: 274.8 MB)

  transpose_convert<<<dim3(HH / 64, D / 64, NE), 256, 0, stream>>>(w1, w1t, D, HH);
  transpose_convert<<<dim3(D / 64, HF / 64, NE), 256, 0, stream>>>(w2, w2t, HF, D);
  gate_kernel<<<S, 256, 0, stream>>>(x, gw, gb, xb, mi0, mi1, mw0, mw1);
  route_kernel<<<1, 1024, 0, stream>>>(mi0, mi1, counts, basep, list_tok, mr0, mr1,
                                       rb_e, rb_row0, rb_n);
  gemm1_kernel<<<dim3(64, MAXRB), 256, 0, stream>>>(xb, w1t, b1, counts, basep, list_tok,
                                                    rb_e, rb_row0, rb_n, act_buf);
  gemm2_kernel<<<dim3(8, MAXRB, 2), 256, 0, stream>>>(act_buf, w2t, counts, basep,
                                                      rb_e, rb_row0, rb_n, oe);
  combine_kernel<<<S, 256, 0, stream>>>(oe, mr0, mr1, mw0, mw1, mi0, mi1, b2, out);
}

// Round 11
// 313.775 us; speedup vs baseline: 1.4333x; 1.1071x over previous
//
#include <hip/hip_runtime.h>
#include <hip/hip_bf16.h>

#define S 2048
#define D 1024
#define NE 8
#define HF 4096
#define HH 8192
#define BK 32
#define ACT_ROWS 4224  // 4096 + 128 pad
#define MAXRB 40       // max 128-row blocks: 4096/128 + 8 - 1 = 39

typedef __attribute__((ext_vector_type(8))) __bf16 bf16x8;
typedef __attribute__((ext_vector_type(4))) float f32x4;

__device__ __forceinline__ unsigned cvtpk(float lo, float hi) {
  unsigned r;
  asm("v_cvt_pk_bf16_f32 %0, %1, %2" : "=v"(r) : "v"(lo), "v"(hi));
  return r;  // RNE, lo in low 16
}
__device__ __forceinline__ unsigned bf16b(float f) {
  unsigned b = __float_as_uint(f);
  return (b + 0x7fffu + ((b >> 16) & 1u)) >> 16;  // RNE fp32->bf16 (finite)
}
__device__ __forceinline__ void gll16(const ushort* g, ushort* l) {
  __builtin_amdgcn_global_load_lds(
      (const __attribute__((address_space(1))) void*)g,
      (__attribute__((address_space(3))) void*)l, 16, 0, 0);
}

// ---- transpose tile body: [R][C] fp32 -> [C][R] bf16, one 64x64 tile ----
__device__ __forceinline__ void transpose_body(const float* __restrict__ Sp,
                                               ushort* __restrict__ Dp, int R, int C,
                                               int n0, int k0, unsigned (*T)[33]) {
  const int t = threadIdx.x;
  const int kp = t >> 4;         // 0..15
  const int nn = (t & 15) * 4;   // 0..60
#pragma unroll
  for (int j = 0; j < 2; ++j) {
    const int ka = k0 + 2 * kp + 32 * j;
    float4 a = *(const float4*)(Sp + (size_t)ka * C + n0 + nn);
    float4 b = *(const float4*)(Sp + (size_t)(ka + 1) * C + n0 + nn);
    T[nn + 0][kp + 16 * j] = cvtpk(a.x, b.x);
    T[nn + 1][kp + 16 * j] = cvtpk(a.y, b.y);
    T[nn + 2][kp + 16 * j] = cvtpk(a.z, b.z);
    T[nn + 3][kp + 16 * j] = cvtpk(a.w, b.w);
  }
  __syncthreads();
  const int n = t >> 2;
  const int kq = (t & 3) * 8;
  uint4 v0 = *(const uint4*)&T[n][kq];
  uint4 v1 = *(const uint4*)&T[n][kq + 4];
  uint4* o = (uint4*)(Dp + (size_t)(n0 + n) * R + k0 + kq * 2);
  o[0] = v0;
  o[1] = v1;
}

// ------- prep: w1 transpose (16384) + w2 transpose (8192) + gate (2048) -------
// All branches: 256 threads, <=8.4KB LDS, BW-bound -> homogeneous occupancy.
union PrepSmem {
  unsigned tr[64][33];
  float sm[4][NE];
};

__global__ __launch_bounds__(256) void prep_kernel(
    const float* __restrict__ w1, ushort* __restrict__ w1t,
    const float* __restrict__ w2, ushort* __restrict__ w2t,
    const float* __restrict__ x, const float* __restrict__ gw,
    const float* __restrict__ gb, ushort* __restrict__ xb,
    int* __restrict__ mi0, int* __restrict__ mi1,
    float* __restrict__ mw0, float* __restrict__ mw1) {
  __shared__ PrepSmem u;
  const int id = blockIdx.x;
  if (id < 16384) {  // w1: R=D, C=HH; 128 n-tiles x 16 k-tiles per expert
    const int e = id >> 11;
    const int rem = id & 2047;
    transpose_body(w1 + (size_t)e * D * HH, w1t + (size_t)e * D * HH, D, HH,
                   (rem & 127) * 64, (rem >> 7) * 64, u.tr);
    return;
  }
  if (id < 24576) {  // w2: R=HF, C=D; 16 n-tiles x 64 k-tiles per expert
    const int id2 = id - 16384;
    const int e = id2 >> 10;
    const int rem = id2 & 1023;
    transpose_body(w2 + (size_t)e * HF * D, w2t + (size_t)e * HF * D, HF, D,
                   (rem & 15) * 64, (rem >> 4) * 64, u.tr);
    return;
  }
  // ---- gate + x->bf16 for token t ----
  const int t = id - 24576;
  const int l = threadIdx.x;  // handles d = 4l..4l+3
  const float4 xv = ((const float4*)(x + (size_t)t * D))[l];
  uint2 wv = {cvtpk(xv.x, xv.y), cvtpk(xv.z, xv.w)};
  ((uint2*)(xb + (size_t)t * D))[l] = wv;

  float xa[4] = {xv.x, xv.y, xv.z, xv.w};
  float acc[NE];
#pragma unroll
  for (int e = 0; e < NE; ++e) acc[e] = 0.f;
  const float* g0 = gw + (size_t)(4 * l) * NE;
#pragma unroll
  for (int j = 0; j < 4; ++j)
#pragma unroll
    for (int e = 0; e < NE; ++e) acc[e] += xa[j] * g0[j * NE + e];
#pragma unroll
  for (int e = 0; e < NE; ++e) {
    float v = acc[e];
#pragma unroll
    for (int off = 32; off > 0; off >>= 1) v += __shfl_xor(v, off);
    acc[e] = v;
  }
  const int wid = l >> 6;
  if ((l & 63) == 0) {
#pragma unroll
    for (int e = 0; e < NE; ++e) u.sm[wid][e] = acc[e];
  }
  __syncthreads();
  if (l == 0) {
    float lg[NE];
#pragma unroll
    for (int e = 0; e < NE; ++e)
      lg[e] = u.sm[0][e] + u.sm[1][e] + u.sm[2][e] + u.sm[3][e] + gb[e];
    int i0 = 0; float m0 = lg[0];
#pragma unroll
    for (int e = 1; e < NE; ++e) if (lg[e] > m0) { m0 = lg[e]; i0 = e; }  // strict >: jax tie-break
    int i1 = -1; float m1 = -3.4e38f;
#pragma unroll
    for (int e = 0; e < NE; ++e) if (e != i0 && lg[e] > m1) { m1 = lg[e]; i1 = e; }
    float p = __expf(m1 - m0);
    float inv = 1.f / (1.f + p);
    mi0[t] = i0; mi1[t] = i1;
    mw0[t] = inv; mw1[t] = p * inv;
  }
}

// --- routing: counts + prefix + slots + compact rowblock table (one block) ---
__global__ __launch_bounds__(1024) void route_kernel(
    const int* __restrict__ mi0, const int* __restrict__ mi1,
    int* __restrict__ counts, int* __restrict__ basep, int* __restrict__ list_tok,
    int* __restrict__ mr0, int* __restrict__ mr1,
    int* __restrict__ rb_e, int* __restrict__ rb_row0, int* __restrict__ rb_n) {
  __shared__ int cnt[NE];
  __shared__ int cur[NE];
  const int t = threadIdx.x;
  if (t < NE) cnt[t] = 0;
  __syncthreads();
  const int e0a = mi0[t], e1a = mi1[t];
  const int e0b = mi0[t + 1024], e1b = mi1[t + 1024];
  atomicAdd(&cnt[e0a], 1); atomicAdd(&cnt[e1a], 1);
  atomicAdd(&cnt[e0b], 1); atomicAdd(&cnt[e1b], 1);
  __syncthreads();
  if (t == 0) {
    int s = 0;
#pragma unroll
    for (int e = 0; e < NE; ++e) { basep[e] = s; cur[e] = s; s += cnt[e]; }
    basep[NE] = s;
    int nrb = 0;
    for (int e = 0; e < NE; ++e)
      for (int r0 = 0; r0 < cnt[e]; r0 += 128) {
        rb_e[nrb] = e; rb_row0[nrb] = r0; ++nrb;
      }
    *rb_n = nrb;  // <= 39
  }
  if (t < NE) counts[t] = cnt[t];
  __syncthreads();
  int r;
  r = atomicAdd(&cur[e0a], 1); list_tok[r] = t; mr0[t] = r;
  r = atomicAdd(&cur[e1a], 1); list_tok[r] = t; mr1[t] = r;
  r = atomicAdd(&cur[e0b], 1); list_tok[r] = t + 1024; mr0[t + 1024] = r;
  r = atomicAdd(&cur[e1b], 1); list_tok[r] = t + 1024; mr1[t + 1024] = r;
}

// -------- GEMM1 + SwiGLU: 128 rows x 64 act-cols (both H halves), 16x16x32 MFMA --------
// grid: x = jt (fastest, 64), y = compact rowblock id (<=40, ~all active)
__global__ __launch_bounds__(256) void gemm1_kernel(
    const ushort* __restrict__ xb, const ushort* __restrict__ w1t,
    const float* __restrict__ b1, const int* __restrict__ counts,
    const int* __restrict__ basep, const int* __restrict__ list_tok,
    const int* __restrict__ rb_e, const int* __restrict__ rb_row0,
    const int* __restrict__ rb_n, ushort* __restrict__ act_buf) {
  const int rb = blockIdx.y;
  if (rb >= *rb_n) return;
  const int e = rb_e[rb];
  const int row0 = rb_row0[rb];
  const int cnt = counts[e];
  const int jt = blockIdx.x * 64;
  const ushort* __restrict__ W = w1t + (size_t)e * D * HH;  // [n=8192][k=1024] bf16
  const int gbase = basep[e];

  __shared__ ushort As[2][128][BK];
  __shared__ ushort Bs[2][128][BK];  // rows 0..63: x-half col jt+n ; 64..127: gate-half

  const int tid = threadIdx.x;
  const int w = tid >> 6;
  const int i = tid & 63;

  const int rA0 = w * 32 + (i >> 2);
  const int rA1 = rA0 + 16;
  int s0 = row0 + rA0; if (s0 >= cnt) s0 = cnt - 1;
  int s1 = row0 + rA1; if (s1 >= cnt) s1 = cnt - 1;
  const ushort* pa0 = xb + (size_t)list_tok[gbase + s0] * D + (i & 3) * 8;
  const ushort* pa1 = xb + (size_t)list_tok[gbase + s1] * D + (i & 3) * 8;
  const ushort* pb0 = W + ((size_t)(rA0 >> 6) * HF + jt + (rA0 & 63)) * D + (i & 3) * 8;
  const ushort* pb1 = W + ((size_t)(rA1 >> 6) * HF + jt + (rA1 & 63)) * D + (i & 3) * 8;

  const int wm = (w >> 1) * 64;
  const int wn = (w & 1) * 32;
  const int lr = i & 15;
  const int kg = i >> 4;

  f32x4 acc[2][4][2] = {};  // [half][mi][ni]

  gll16(pa0, &As[0][w * 32][0]);
  gll16(pa1, &As[0][w * 32 + 16][0]);
  gll16(pb0, &Bs[0][w * 32][0]);
  gll16(pb1, &Bs[0][w * 32 + 16][0]);
  __syncthreads();

  int cur = 0;
#pragma unroll 1
  for (int it = 0; it < D / BK; ++it) {
    if (it + 1 < D / BK) {
      const int ko = (it + 1) * BK;
      gll16(pa0 + ko, &As[cur ^ 1][w * 32][0]);
      gll16(pa1 + ko, &As[cur ^ 1][w * 32 + 16][0]);
      gll16(pb0 + ko, &Bs[cur ^ 1][w * 32][0]);
      gll16(pb1 + ko, &Bs[cur ^ 1][w * 32 + 16][0]);
    }
    bf16x8 af[4], bfr[2][2];
#pragma unroll
    for (int mi = 0; mi < 4; ++mi)
      af[mi] = *(const bf16x8*)&As[cur][wm + mi * 16 + lr][kg * 8];
#pragma unroll
    for (int h = 0; h < 2; ++h)
#pragma unroll
      for (int ni = 0; ni < 2; ++ni)
        bfr[h][ni] = *(const bf16x8*)&Bs[cur][h * 64 + wn + ni * 16 + lr][kg * 8];
#pragma unroll
    for (int h = 0; h < 2; ++h)
#pragma unroll
      for (int mi = 0; mi < 4; ++mi)
#pragma unroll
        for (int ni = 0; ni < 2; ++ni)
          acc[h][mi][ni] = __builtin_amdgcn_mfma_f32_16x16x32_bf16(af[mi], bfr[h][ni],
                                                                   acc[h][mi][ni], 0, 0, 0);
    __syncthreads();
    cur ^= 1;
  }

#pragma unroll
  for (int mi = 0; mi < 4; ++mi)
#pragma unroll
    for (int ni = 0; ni < 2; ++ni) {
      const int c = jt + wn + ni * 16 + lr;
      const float bx = b1[(size_t)e * HH + c];
      const float bg = b1[(size_t)e * HH + HF + c];
      f32x4 vx = acc[0][mi][ni];
      f32x4 vg = acc[1][mi][ni];
#pragma unroll
      for (int q = 0; q < 4; ++q) {
        const int slot = row0 + wm + mi * 16 + kg * 4 + q;
        if (slot < cnt) {
          float xv = vx[q] + bx;
          float g = vg[q] + bg;
          float a = g / (1.f + __expf(-g)) * xv;
          act_buf[(size_t)(gbase + slot) * HF + c] = (ushort)bf16b(a);
        }
      }
    }
}

// -------- GEMM2 (K-split 2): oe[split] = act @ W2[e], bf16 stores --------
// grid: x = jt (fastest, 8), y = compact rowblock id, z = split
__global__ __launch_bounds__(256) void gemm2_kernel(
    const ushort* __restrict__ act_buf, const ushort* __restrict__ w2t,
    const int* __restrict__ counts, const int* __restrict__ basep,
    const int* __restrict__ rb_e, const int* __restrict__ rb_row0,
    const int* __restrict__ rb_n, ushort* __restrict__ oe) {
  const int rb = blockIdx.y;
  if (rb >= *rb_n) return;
  const int e = rb_e[rb];
  const int row0 = rb_row0[rb];
  const int cnt = counts[e];
  const int split = blockIdx.z;
  const int jt = blockIdx.x * 128;
  const ushort* __restrict__ W = w2t + (size_t)e * HF * D;  // [n=1024][kf=4096] bf16
  const int gbase = basep[e];

  __shared__ ushort As[2][128][BK];
  __shared__ ushort Bs[2][128][BK];

  const int tid = threadIdx.x;
  const int w = tid >> 6;
  const int i = tid & 63;

  const int r0 = w * 32 + (i >> 2);
  const size_t kbase = (size_t)split * (HF / 2);
  const ushort* pa0 = act_buf + (size_t)(gbase + row0 + r0) * HF + kbase + (i & 3) * 8;
  const ushort* pa1 = pa0 + (size_t)16 * HF;
  const ushort* pb0 = W + (size_t)(jt + r0) * HF + kbase + (i & 3) * 8;
  const ushort* pb1 = pb0 + (size_t)16 * HF;

  const int wm = (w >> 1) * 64;
  const int wn = (w & 1) * 64;
  const int lr = i & 15;
  const int kg = i >> 4;

  f32x4 acc[4][4] = {};

  gll16(pa0, &As[0][w * 32][0]);
  gll16(pa1, &As[0][w * 32 + 16][0]);
  gll16(pb0, &Bs[0][w * 32][0]);
  gll16(pb1, &Bs[0][w * 32 + 16][0]);
  __syncthreads();

  int cur = 0;
#pragma unroll 1
  for (int it = 0; it < (HF / 2) / BK; ++it) {
    if (it + 1 < (HF / 2) / BK) {
      const int ko = (it + 1) * BK;
      gll16(pa0 + ko, &As[cur ^ 1][w * 32][0]);
      gll16(pa1 + ko, &As[cur ^ 1][w * 32 + 16][0]);
      gll16(pb0 + ko, &Bs[cur ^ 1][w * 32][0]);
      gll16(pb1 + ko, &Bs[cur ^ 1][w * 32 + 16][0]);
    }
    bf16x8 af[4], bfr[4];
#pragma unroll
    for (int mi = 0; mi < 4; ++mi)
      af[mi] = *(const bf16x8*)&As[cur][wm + mi * 16 + lr][kg * 8];
#pragma unroll
    for (int ni = 0; ni < 4; ++ni)
      bfr[ni] = *(const bf16x8*)&Bs[cur][wn + ni * 16 + lr][kg * 8];
#pragma unroll
    for (int mi = 0; mi < 4; ++mi)
#pragma unroll
      for (int ni = 0; ni < 4; ++ni)
        acc[mi][ni] = __builtin_amdgcn_mfma_f32_16x16x32_bf16(af[mi], bfr[ni],
                                                              acc[mi][ni], 0, 0, 0);
    __syncthreads();
    cur ^= 1;
  }

#pragma unroll
  for (int mi = 0; mi < 4; ++mi)
#pragma unroll
    for (int ni = 0; ni < 4; ++ni) {
      f32x4 v = acc[mi][ni];
#pragma unroll
      for (int q = 0; q < 4; ++q) {
        const int slot = row0 + wm + mi * 16 + kg * 4 + q;
        if (slot < cnt)
          oe[((size_t)split * ACT_ROWS + gbase + slot) * D + jt + wn + ni * 16 + lr] =
              (ushort)bf16b(v[q]);
      }
    }
}

// ---- combine: out[t] = w0*(sum_s oe[s][r0] + b2[e0]) + w1*(sum_s oe[s][r1] + b2[e1]) ----
__global__ void combine_kernel(const ushort* __restrict__ oe,
                               const int* __restrict__ mr0, const int* __restrict__ mr1,
                               const float* __restrict__ mw0, const float* __restrict__ mw1,
                               const int* __restrict__ mi0, const int* __restrict__ mi1,
                               const float* __restrict__ b2, float* __restrict__ out) {
  const int t = blockIdx.x;
  const int l = threadIdx.x;  // 4 elems per thread
  const float w0 = mw0[t], w1 = mw1[t];
  const int r0 = mr0[t], r1 = mr1[t];
  float a0[4] = {0.f, 0.f, 0.f, 0.f}, a1[4] = {0.f, 0.f, 0.f, 0.f};
#pragma unroll
  for (int s = 0; s < 2; ++s) {
    uint2 u0 = *(const uint2*)(oe + ((size_t)s * ACT_ROWS + r0) * D + l * 4);
    uint2 u1 = *(const uint2*)(oe + ((size_t)s * ACT_ROWS + r1) * D + l * 4);
    a0[0] += __uint_as_float(u0.x << 16);
    a0[1] += __uint_as_float(u0.x & 0xffff0000u);
    a0[2] += __uint_as_float(u0.y << 16);
    a0[3] += __uint_as_float(u0.y & 0xffff0000u);
    a1[0] += __uint_as_float(u1.x << 16);
    a1[1] += __uint_as_float(u1.x & 0xffff0000u);
    a1[2] += __uint_as_float(u1.y << 16);
    a1[3] += __uint_as_float(u1.y & 0xffff0000u);
  }
  float4 c0 = ((const float4*)(b2 + (size_t)mi0[t] * D))[l];
  float4 c1 = ((const float4*)(b2 + (size_t)mi1[t] * D))[l];
  float4 r;
  r.x = w0 * (a0[0] + c0.x) + w1 * (a1[0] + c1.x);
  r.y = w0 * (a0[1] + c0.y) + w1 * (a1[1] + c1.y);
  r.z = w0 * (a0[2] + c0.z) + w1 * (a1[2] + c1.z);
  r.w = w0 * (a0[3] + c0.w) + w1 * (a1[3] + c1.w);
  ((float4*)(out + (size_t)t * D))[l] = r;
}

extern "C" void kernel_launch(void* const* d_in, const int* in_sizes, int n_in,
                              void* d_out, int out_size, void* d_ws, size_t ws_size,
                              hipStream_t stream) {
  const float* x  = (const float*)d_in[0];
  const float* gw = (const float*)d_in[1];
  const float* gb = (const float*)d_in[2];
  const float* w1 = (const float*)d_in[3];
  const float* b1 = (const float*)d_in[4];
  const float* w2 = (const float*)d_in[5];
  const float* b2 = (const float*)d_in[6];
  float* out = (float*)d_out;

  char* ws = (char*)d_ws;
  int*   counts   = (int*)(ws + 0);
  int*   basep    = (int*)(ws + 64);
  int*   rb_n     = (int*)(ws + 128);
  int*   rb_e     = (int*)(ws + 192);                       // 40 ints
  int*   rb_row0  = (int*)(ws + 384);                       // 40 ints
  int*   mi0      = (int*)(ws + 1024);
  int*   mi1      = (int*)(ws + 1024 + 1 * 8192);
  int*   mr0      = (int*)(ws + 1024 + 2 * 8192);
  int*   mr1      = (int*)(ws + 1024 + 3 * 8192);
  float* mw0      = (float*)(ws + 1024 + 4 * 8192);
  float* mw1      = (float*)(ws + 1024 + 5 * 8192);
  int*   list_tok = (int*)(ws + 1024 + 6 * 8192);           // 16384 B -> ends 66560
  ushort* xb      = (ushort*)(ws + 66560);                  // 4 MB
  ushort* act_buf = (ushort*)(ws + 4260864);                // 34.6 MB (4224 x 4096 bf16)
  ushort* oe      = (ushort*)(ws + 38863872);               // 17.3 MB (2 x 4224 x 1024 bf16)
  ushort* w1t     = (ushort*)(ws + 73466880);               // 134 MB
  ushort* w2t     = (ushort*)(ws + 207684608);              // 67 MB (end: 274.8 MB)

  prep_kernel<<<16384 + 8192 + S, 256, 0, stream>>>(w1, w1t, w2, w2t, x, gw, gb, xb,
                                                    mi0, mi1, mw0, mw1);
  route_kernel<<<1, 1024, 0, stream>>>(mi0, mi1, counts, basep, list_tok, mr0, mr1,
                                       rb_e, rb_row0, rb_n);
  gemm1_kernel<<<dim3(64, MAXRB), 256, 0, stream>>>(xb, w1t, b1, counts, basep, list_tok,
                                                    rb_e, rb_row0, rb_n, act_buf);
  gemm2_kernel<<<dim3(8, MAXRB, 2), 256, 0, stream>>>(act_buf, w2t, counts, basep,
                                                      rb_e, rb_row0, rb_n, oe);
  combine_kernel<<<S, 256, 0, stream>>>(oe, mr0, mr1, mw0, mw1, mi0, mi1, b2, out);
}